// Round 12
// baseline (34.191 us; speedup 1.0000x reference)
//
#include <hip/hip_runtime.h>

#define SEQ 128
#define SD  15
#define REC 32    // floats per (b,s) record in dba_params
#define RPB 2     // rows per block
#define NT  (RPB * SEQ)   // 256 threads, 4 waves

// ---------------------------------------------------------------------------
// R5's winning structure at half the block grain: 2048 blocks x 256 threads
// = 8 blocks/CU, 32 waves/CU (same residency as the 27.8us R5, but 2x more
// independent phase streams per CU for the scheduler to interleave).
// Store-placement rules (empirically ranked over R5..R10):
//   1. dba/gt loads issue FIRST (they feed the serial chains).
//   2. Non-critical stores (zeros, pos, t=0 quat) go between scan and chain
//      — they drain while the chain runs (hidden).
//   3. Only the 4-float quat store is exposed post-chain.
//   4. Chain never touches global memory (LDS in, LDS out).
// ---------------------------------------------------------------------------
__global__ __launch_bounds__(NT, 8) void fused_kernel(const float* __restrict__ dba,
                                                      const float* __restrict__ gt,
                                                      float* __restrict__ out,
                                                      int B) {
    const int tid  = threadIdx.x;
    const int row  = tid >> 7;          // 0..1
    const int s    = tid & (SEQ - 1);   // 0..127
    const int lane = tid & 63;
    const int half = s >> 6;            // which of the row's two waves
    const int r    = blockIdx.x * RPB + row;
    const bool valid = (r < B);

    __shared__ float4 sdq  [RPB][SEQ + 1];   // +1 pad: chain lanes on distinct banks
    __shared__ float4 squat[RPB][SEQ + 1];
    __shared__ float  ginit[RPB][8];
    __shared__ float  w0tot[RPB][3];

    // ---- P1: loads issue first ----
    float d0 = 0.f, d1 = 0.f, d2 = 0.f;
    if (valid) {
        const float* rec = dba + ((size_t)r * SEQ + s) * REC;
        const float4 h0 = *reinterpret_cast<const float4*>(rec);
        const float4 h1 = *reinterpret_cast<const float4*>(rec + 4);
        sdq[row][s] = make_float4(h0.w * 0.1f, h1.x * 0.1f, h1.y * 0.1f, h1.z * 0.1f);
        d0 = h0.x * 0.1f; d1 = h0.y * 0.1f; d2 = h0.z * 0.1f;
        if (s == 0) {
            const float* g = gt + (size_t)r * SEQ * SD;
            *reinterpret_cast<float4*>(&ginit[row][0]) = *reinterpret_cast<const float4*>(g);
            *reinterpret_cast<float4*>(&ginit[row][4]) = *reinterpret_cast<const float4*>(g + 4);
        }
    }

    float ix = d0, iy = d1, iz = d2;       // wave-local inclusive scan
#pragma unroll
    for (int off = 1; off < 64; off <<= 1) {
        const float tx = __shfl_up(ix, off, 64);
        const float ty = __shfl_up(iy, off, 64);
        const float tz = __shfl_up(iz, off, 64);
        if (lane >= off) { ix += tx; iy += ty; iz += tz; }
    }
    if (half == 0 && lane == 63) {
        w0tot[row][0] = ix; w0tot[row][1] = iy; w0tot[row][2] = iz;
    }
    __syncthreads();
    if (half == 1) { ix += w0tot[row][0]; iy += w0tot[row][1]; iz += w0tot[row][2]; }

    // ---- P2a: hidden stores (pos, zeros, t=0 quat) — drain under the chain ----
    float* o = out + ((size_t)r * SEQ + s) * SD;
    if (valid) {
        o[0] = ginit[row][0] + ix - d0;   // exclusive prefix = inclusive - own
        o[1] = ginit[row][1] + iy - d1;
        o[2] = ginit[row][2] + iz - d2;
        if (s == 0) {                     // t=0 quat: init_q, NOT normalized
            o[3] = ginit[row][3]; o[4] = ginit[row][4];
            o[5] = ginit[row][5]; o[6] = ginit[row][6];
        }
#pragma unroll
        for (int k = 7; k < SD; ++k) o[k] = 0.f;
    }

    // ---- P2b: quaternion chains, lanes 0..1 of wave 0, quats -> LDS ----
    if (tid < RPB && blockIdx.x * RPB + tid < B) {
        const float4* srow = sdq[tid];
        float4*       qrow = squat[tid];
        float q0 = ginit[tid][3], q1 = ginit[tid][4],
              q2 = ginit[tid][5], q3 = ginit[tid][6];

#define QSTEP(C, T) do {                                                \
            q0 += (C).x; q1 += (C).y; q2 += (C).z; q3 += (C).w;         \
            const float a_ = q0 * q0 + q1 * q1;                         \
            const float b_ = q2 * q2 + q3 * q3;                         \
            const float i_ = __builtin_amdgcn_rsqf(a_ + b_);            \
            q0 *= i_; q1 *= i_; q2 *= i_; q3 *= i_;                     \
            qrow[T] = make_float4(q0, q1, q2, q3);                      \
        } while (0)

        float4 c0 = srow[0], c1 = srow[1], c2 = srow[2], c3 = srow[3],
               c4 = srow[4], c5 = srow[5], c6 = srow[6], c7 = srow[7];
        for (int w = 0; w < 15; ++w) {               // t = 1..120
            const float4* nx = srow + (w + 1) * 8;   // last window: srow[120..127]
            const float4 n0 = nx[0], n1 = nx[1], n2 = nx[2], n3 = nx[3],
                         n4 = nx[4], n5 = nx[5], n6 = nx[6], n7 = nx[7];
            const int t = w * 8 + 1;
            QSTEP(c0, t);     QSTEP(c1, t + 1); QSTEP(c2, t + 2); QSTEP(c3, t + 3);
            QSTEP(c4, t + 4); QSTEP(c5, t + 5); QSTEP(c6, t + 6); QSTEP(c7, t + 7);
            c0 = n0; c1 = n1; c2 = n2; c3 = n3;
            c4 = n4; c5 = n5; c6 = n6; c7 = n7;
        }
        QSTEP(c0, 121); QSTEP(c1, 122); QSTEP(c2, 123); QSTEP(c3, 124);
        QSTEP(c4, 125); QSTEP(c5, 126); QSTEP(c6, 127);
#undef QSTEP
    }
    __syncthreads();

    // ---- P3: only the s>=1 quat store is exposed post-chain ----
    if (valid && s > 0) {
        const float4 q = squat[row][s];
        o[3] = q.x; o[4] = q.y; o[5] = q.z; o[6] = q.w;
    }
}

extern "C" void kernel_launch(void* const* d_in, const int* in_sizes, int n_in,
                              void* d_out, int out_size, void* d_ws, size_t ws_size,
                              hipStream_t stream) {
    const float* dba = (const float*)d_in[0];   // (B, 128, 32)
    // d_in[1] = imu_measurements — unused by the reference
    const float* gt  = (const float*)d_in[2];   // (B, 128, 15)
    float* out = (float*)d_out;                 // (B, 128, 15)

    const int B = in_sizes[0] / (SEQ * REC);
    const int blocks = (B + RPB - 1) / RPB;     // 2048 @ B=4096 -> 8 blocks/CU
    fused_kernel<<<blocks, NT, 0, stream>>>(dba, gt, out, B);
}

// Round 13
// 32.232 us; speedup vs baseline: 1.0608x; 1.0608x over previous
//
#include <hip/hip_runtime.h>

#define SEQ 128
#define SD  15
#define REC 32    // floats per (b,s) record in dba_params
#define WPB 4     // waves per block, ONE ROW PER WAVE
#define NT  (WPB * 64)   // 256 threads

// ---------------------------------------------------------------------------
// Barrier-free kernel: one batch row per WAVE, zero __syncthreads.
// R5..R11 post-mortem: every variant shared block-wide barriers; with the
// whole grid exactly-resident, the chip ran load-burst -> chain-bubble ->
// store-burst in lockstep, each phase alone at ~2.4 TB/s. Here each wave is
// fully independent (private LDS region, wave-internal s_waitcnt handoffs),
// so waves drift on memory jitter and loads/chains/stores of different waves
// interleave continuously.
//  - lane l owns records 2l, 2l+1 (two consecutive 128 B records).
//  - wave-scan of per-lane pair sums -> exclusive position prefixes.
//  - lane 0 runs the 127-step quat chain from the wave's sdq region (8-deep
//    named-register window), writing quats straight into the packed image.
//  - wave stores its row as 480 contiguous float4s (full-line writes).
// ---------------------------------------------------------------------------
__global__ __launch_bounds__(NT, 4) void fused_kernel(const float* __restrict__ dba,
                                                      const float* __restrict__ gt,
                                                      float* __restrict__ out,
                                                      int B) {
    const int tid  = threadIdx.x;
    const int wave = tid >> 6;
    const int lane = tid & 63;
    const int r    = blockIdx.x * WPB + wave;
    if (r >= B) return;                       // wave-uniform exit

    __shared__ float4 sdq [WPB][SEQ];         // 8 KB: pre-scaled dq per wave
    __shared__ float  pack[WPB][SEQ * SD];    // 30 KB: packed output rows

    // ---- P1: loads (2 records/lane + broadcast gt head) ----
    const float* rec0 = dba + ((size_t)r * SEQ + 2 * lane) * REC;
    const float4 h0a = *reinterpret_cast<const float4*>(rec0);
    const float4 h0b = *reinterpret_cast<const float4*>(rec0 + 4);
    const float4 h1a = *reinterpret_cast<const float4*>(rec0 + REC);
    const float4 h1b = *reinterpret_cast<const float4*>(rec0 + REC + 4);
    const float* g   = gt + (size_t)r * SEQ * SD;
    const float4 gA  = *reinterpret_cast<const float4*>(g);      // pos.xyz, q0
    const float4 gB  = *reinterpret_cast<const float4*>(g + 4);  // q1,q2,q3,-

    sdq[wave][2 * lane]     = make_float4(h0a.w * 0.1f, h0b.x * 0.1f,
                                          h0b.y * 0.1f, h0b.z * 0.1f);
    sdq[wave][2 * lane + 1] = make_float4(h1a.w * 0.1f, h1b.x * 0.1f,
                                          h1b.y * 0.1f, h1b.z * 0.1f);

    const float d0x = h0a.x * 0.1f, d0y = h0a.y * 0.1f, d0z = h0a.z * 0.1f;
    const float d1x = h1a.x * 0.1f, d1y = h1a.y * 0.1f, d1z = h1a.z * 0.1f;

    // ---- wave scan of per-lane pair sums ----
    const float sx = d0x + d1x, sy = d0y + d1y, sz = d0z + d1z;
    float ix = sx, iy = sy, iz = sz;
#pragma unroll
    for (int off = 1; off < 64; off <<= 1) {
        const float tx = __shfl_up(ix, off, 64);
        const float ty = __shfl_up(iy, off, 64);
        const float tz = __shfl_up(iz, off, 64);
        if (lane >= off) { ix += tx; iy += ty; iz += tz; }
    }
    const float ex = ix - sx, ey = iy - sy, ez = iz - sz;  // records < 2*lane

    // ---- pack pos + zeros (+ lane0: t=0 quat) ----
    float* pw = pack[wave];
    {
        float* p0 = pw + (2 * lane) * SD;
        p0[0] = gA.x + ex; p0[1] = gA.y + ey; p0[2] = gA.z + ez;
#pragma unroll
        for (int k = 7; k < SD; ++k) p0[k] = 0.f;
        float* p1 = p0 + SD;
        p1[0] = gA.x + ex + d0x; p1[1] = gA.y + ey + d0y; p1[2] = gA.z + ez + d0z;
#pragma unroll
        for (int k = 7; k < SD; ++k) p1[k] = 0.f;
        if (lane == 0) {                      // t=0 quat: init_q, NOT normalized
            pw[3] = gA.w; pw[4] = gB.x; pw[5] = gB.y; pw[6] = gB.z;
        }
    }

    // wave-internal LDS fence: all lanes' sdq/pack writes visible to lane 0
    asm volatile("s_waitcnt lgkmcnt(0)" ::: "memory");

    // ---- chain: lane 0 only, 8-deep named window, quats -> packed image ----
    if (lane == 0) {
        const float4* srow = sdq[wave];
        float* qp = pw + SD + 3;              // quat slot of t=1
        float q0 = gA.w, q1 = gB.x, q2 = gB.y, q3 = gB.z;

#define QSTEP(C) do {                                                   \
            q0 += (C).x; q1 += (C).y; q2 += (C).z; q3 += (C).w;         \
            const float a_ = q0 * q0 + q1 * q1;                         \
            const float b_ = q2 * q2 + q3 * q3;                         \
            const float i_ = __builtin_amdgcn_rsqf(a_ + b_);            \
            q0 *= i_; q1 *= i_; q2 *= i_; q3 *= i_;                     \
            qp[0] = q0; qp[1] = q1; qp[2] = q2; qp[3] = q3;             \
            qp += SD;                                                   \
        } while (0)

        float4 c0 = srow[0], c1 = srow[1], c2 = srow[2], c3 = srow[3],
               c4 = srow[4], c5 = srow[5], c6 = srow[6], c7 = srow[7];
        for (int w = 0; w < 15; ++w) {               // t = 1..120
            const float4* nx = srow + (w + 1) * 8;   // last window: srow[120..127]
            const float4 n0 = nx[0], n1 = nx[1], n2 = nx[2], n3 = nx[3],
                         n4 = nx[4], n5 = nx[5], n6 = nx[6], n7 = nx[7];
            QSTEP(c0); QSTEP(c1); QSTEP(c2); QSTEP(c3);
            QSTEP(c4); QSTEP(c5); QSTEP(c6); QSTEP(c7);
            c0 = n0; c1 = n1; c2 = n2; c3 = n3;
            c4 = n4; c5 = n5; c6 = n6; c7 = n7;
        }
        QSTEP(c0); QSTEP(c1); QSTEP(c2); QSTEP(c3);  // t = 121..127
        QSTEP(c4); QSTEP(c5); QSTEP(c6);
#undef QSTEP
    }

    // wave-internal LDS fence: lane 0's quat writes visible to all lanes
    asm volatile("s_waitcnt lgkmcnt(0)" ::: "memory");

    // ---- store: row as 480 contiguous float4s (full-line writes) ----
    float4* o4 = reinterpret_cast<float4*>(out + (size_t)r * SEQ * SD);
    const float4* s4 = reinterpret_cast<const float4*>(pw);
#pragma unroll
    for (int k = lane; k < SEQ * SD / 4; k += 64)    // 480 = 7*64 + 32
        o4[k] = s4[k];
}

extern "C" void kernel_launch(void* const* d_in, const int* in_sizes, int n_in,
                              void* d_out, int out_size, void* d_ws, size_t ws_size,
                              hipStream_t stream) {
    const float* dba = (const float*)d_in[0];   // (B, 128, 32)
    // d_in[1] = imu_measurements — unused by the reference
    const float* gt  = (const float*)d_in[2];   // (B, 128, 15)
    float* out = (float*)d_out;                 // (B, 128, 15)

    const int B = in_sizes[0] / (SEQ * REC);
    const int blocks = (B + WPB - 1) / WPB;     // 1024 @ B=4096
    fused_kernel<<<blocks, NT, 0, stream>>>(dba, gt, out, B);
}